// Round 4
// baseline (6147.217 us; speedup 1.0000x reference)
//
#include <hip/hip_runtime.h>

#define NUMS   128
#define NVARS  16
#define BATCH  8192
#define ITERS  15

// d_out element offsets (return order: cv, cp, cr, acc_fixed, acc_primal, primal_stack, fixed_stack)
#define OUT_ACCF (3*BATCH*NVARS)           // 393216
#define OUT_ACCP (OUT_ACCF + BATCH)        // 401408
#define OUT_PST  (OUT_ACCP + BATCH)        // 409600
#define OUT_FST  (OUT_PST + ITERS*BATCH)   // 532480

// ---------------------------------------------------------------------------
// prep: AtA = 2(P^T P + Pd^T Pd + Pdd^T Pdd); cost_mat = [[I+AtA, Aeq^T],[Aeq,0]];
// M = inv(cost_mat) via f64 Gauss-Jordan. ws: [0,324) M row-major f32,
// [324,596) AtA padded [16][17] f32.
// ---------------------------------------------------------------------------
__global__ void prep_kernel(const float* __restrict__ P, const float* __restrict__ Pd,
                            const float* __restrict__ Pdd, float* __restrict__ ws)
{
    __shared__ double GA[18][36];
    __shared__ float  ata[16][16];
    __shared__ double piv_s;
    const int t = threadIdx.x;

    if (t < 256) {
        int j = t >> 4, k = t & 15;
        float s = 0.f;
        for (int i = 0; i < NUMS; ++i)
            s += P[i*16+j]*P[i*16+k] + Pd[i*16+j]*Pd[i*16+k] + Pdd[i*16+j]*Pdd[i*16+k];
        ata[j][k] = 2.f * s;
    }
    __syncthreads();

    const int gi = t / 36, gj = t % 36;   // blockDim = 648
    {
        double v;
        if (gj < 18) {
            if (gi < 16 && gj < 16)      v = (gi == gj ? 1.0 : 0.0) + (double)ata[gi][gj];
            else if (gi < 16)            v = (gj == 16) ? (double)P[gi] : (double)Pd[gi];
            else if (gj < 16)            v = (gi == 16) ? (double)P[gj] : (double)Pd[gj];
            else                         v = 0.0;
        } else {
            v = ((gj - 18) == gi) ? 1.0 : 0.0;
        }
        GA[gi][gj] = v;
    }
    __syncthreads();

    for (int k = 0; k < 18; ++k) {
        if (t == 0) piv_s = GA[k][k];
        __syncthreads();
        if (gi == k) GA[gi][gj] /= piv_s;
        __syncthreads();
        double f  = GA[gi][k];
        double rk = GA[k][gj];
        __syncthreads();
        if (gi != k) GA[gi][gj] -= f * rk;
        __syncthreads();
    }

    if (gj >= 18) ws[gi*18 + (gj - 18)] = (float)GA[gi][gj];
    if (t < 256)  ws[324 + (t >> 4)*17 + (t & 15)] = ata[t >> 4][t & 15];
    if (t >= 256 && t < 272) ws[324 + (t - 256)*17 + 16] = 0.f;
}

// ---------------------------------------------------------------------------
// main solver: block = 192 threads = 12 groups of 16 lanes = 4 rows x 3 channels.
// State is DISTRIBUTED: lane l of a group owns component l of c, L, cq, pj.
// (Replicated state spilled to scratch -> 9 GB HBM traffic in R1.)
// ---------------------------------------------------------------------------
__launch_bounds__(192, 4)
__global__ void solve_kernel(
    const float* __restrict__ P,    const float* __restrict__ Pd,   const float* __restrict__ Pdd,
    const float* __restrict__ lamv, const float* __restrict__ lamp, const float* __restrict__ lamr,
    const float* __restrict__ cinv, const float* __restrict__ cinp, const float* __restrict__ cinr,
    const float* __restrict__ beqv, const float* __restrict__ beqp, const float* __restrict__ beqr,
    const float* __restrict__ c0v,  const float* __restrict__ c0p,  const float* __restrict__ c0r,
    float* __restrict__ out, const float* __restrict__ ws)
{
    __shared__ __align__(16) float Pt[3][16][128];   // transposed: Pt[m][j][i]
    __shared__ float Ml[16][19];                     // M rows 0..15, cols 0..17 (pad 19)
    __shared__ float ata[16][17];
    __shared__ float res_st[ITERS][12];
    __shared__ float fix_st[ITERS][12];

    // ---- stage constants ----
#pragma unroll
    for (int m = 0; m < 3; ++m) {
        const float* src = (m == 0) ? P : (m == 1) ? Pd : Pdd;
        for (int f = threadIdx.x; f < 2048; f += 192) {
            int j = f >> 7, i = f & 127;
            Pt[m][j][i] = src[i*16 + j];
        }
    }
    for (int f = threadIdx.x; f < 288; f += 192) Ml[f / 18][f % 18] = ws[f];
    for (int f = threadIdx.x; f < 272; f += 192) ((float*)ata)[f] = ws[324 + f];
    __syncthreads();

    const int g  = threadIdx.x >> 4;   // group 0..11
    const int l  = threadIdx.x & 15;   // lane-in-group
    const int rl = g / 3;              // local row 0..3
    const int ch = g - rl * 3;         // channel 0..2
    const int row = blockIdx.x * 4 + rl;

    const float* lam_p = (ch == 0) ? lamv : (ch == 1) ? lamp : lamr;
    const float* cin_p = (ch == 0) ? cinv : (ch == 1) ? cinp : cinr;
    const float* beq_p = (ch == 0) ? beqv : (ch == 1) ? beqp : beqr;
    const float* c0_p  = (ch == 0) ? c0v  : (ch == 1) ? c0p  : c0r;

    // bounds per (ch, m)
    float bmax[3], bmin[3];
    bmax[0] = (ch == 0) ? 20.f : (ch == 1) ? 0.2f  : 0.25f;
    bmin[0] = (ch == 0) ? 12.f : (ch == 1) ? -0.2f : -0.25f;
    bmax[1] = (ch == 0) ? 3.f  : 0.25f;
    bmin[1] = (ch == 0) ? -3.f : -0.25f;
    bmax[2] = (ch == 0) ? 3.f  : 0.15f;
    bmin[2] = (ch == 0) ? -3.f : -0.15f;

    // ---- distributed per-unit state: lane l owns component l ----
    float c_l  = c0_p[row * 16 + l];
    float L_l  = lam_p[row * 16 + l] + cin_p[row * 16 + l];
    float pj_l, cq_l;
    const float beq0 = beq_p[row * 2];
    const float beq1 = beq_p[row * 2 + 1];
    float uo[3][8];                    // lane's 8 constraint rows per derivative order

    // ---- init pass: uo, pj0, cq0 from c0 ----
    {
        float cb[16];
#pragma unroll
        for (int k = 0; k < 16; ++k) cb[k] = __shfl(c_l, k, 16);

        float cqd = 0.f;
#pragma unroll
        for (int k = 0; k < 16; ++k) cqd += ata[l][k] * cb[k];
        cq_l = cqd;

        float pjp[16];
#pragma unroll
        for (int j = 0; j < 16; ++j) pjp[j] = 0.f;
#pragma unroll
        for (int m = 0; m < 3; ++m) {
            float un[8], h[8];
#pragma unroll
            for (int k = 0; k < 8; ++k) un[k] = 0.f;
#pragma unroll
            for (int j = 0; j < 16; ++j) {
                float4 p0 = *(const float4*)&Pt[m][j][4*l];
                float4 p1 = *(const float4*)&Pt[m][j][64 + 4*l];
                un[0] += cb[j]*p0.x; un[1] += cb[j]*p0.y; un[2] += cb[j]*p0.z; un[3] += cb[j]*p0.w;
                un[4] += cb[j]*p1.x; un[5] += cb[j]*p1.y; un[6] += cb[j]*p1.z; un[7] += cb[j]*p1.w;
            }
#pragma unroll
            for (int k = 0; k < 8; ++k) {
                float x = un[k] - bmax[m];
                float rvp = fmaxf(x, 0.f);
                float y = un[k] - bmin[m];
                float rvm = fmaxf(-y, 0.f);
                h[k] = rvp - rvm;
                uo[m][k] = un[k];
            }
#pragma unroll
            for (int j = 0; j < 16; ++j) {
                float4 p0 = *(const float4*)&Pt[m][j][4*l];
                float4 p1 = *(const float4*)&Pt[m][j][64 + 4*l];
                pjp[j] += h[0]*p0.x + h[1]*p0.y + h[2]*p0.z + h[3]*p0.w
                        + h[4]*p1.x + h[5]*p1.y + h[6]*p1.z + h[7]*p1.w;
            }
        }
#pragma unroll
        for (int s = 1; s < 16; s <<= 1) {
#pragma unroll
            for (int j = 0; j < 16; ++j) pjp[j] += __shfl_xor(pjp[j], s, 16);
        }
        float pjl = pjp[0];
#pragma unroll
        for (int k = 1; k < 16; ++k) pjl = (l == k) ? pjp[k] : pjl;
        pj_l = pjl;
    }

    // ---- 15 ADMM iterations ----
    for (int t = 0; t < ITERS; ++t) {
        // KKT solve: rhs_k = L_k + cq_k - pj_k (distributed); lane l owns M row l
        float r_l = L_l + cq_l - pj_l;
        float sj = Ml[l][16] * beq0 + Ml[l][17] * beq1;
#pragma unroll
        for (int k = 0; k < 16; ++k) sj += Ml[l][k] * __shfl(r_l, k, 16);

        float d = sj - c_l;
        float cdel2 = d * d;           // per-lane partial of ||c_new - c_old||^2
        c_l = sj;

        // broadcast new c
        float cb[16];
#pragma unroll
        for (int k = 0; k < 16; ++k) cb[k] = __shfl(c_l, k, 16);

        // cq for next solve: lane l computes (AtA c)_l
        float cqd = 0.f;
#pragma unroll
        for (int k = 0; k < 16; ++k) cqd += ata[l][k] * cb[k];
        cq_l = cqd;

        // projection passes
        float res2 = 0.f, ds2 = 0.f;
        float pjp[16];
#pragma unroll
        for (int j = 0; j < 16; ++j) pjp[j] = 0.f;

#pragma unroll
        for (int m = 0; m < 3; ++m) {
            float un[8], h[8];
#pragma unroll
            for (int k = 0; k < 8; ++k) un[k] = 0.f;
#pragma unroll
            for (int j = 0; j < 16; ++j) {
                float4 p0 = *(const float4*)&Pt[m][j][4*l];
                float4 p1 = *(const float4*)&Pt[m][j][64 + 4*l];
                un[0] += cb[j]*p0.x; un[1] += cb[j]*p0.y; un[2] += cb[j]*p0.z; un[3] += cb[j]*p0.w;
                un[4] += cb[j]*p1.x; un[5] += cb[j]*p1.y; un[6] += cb[j]*p1.z; un[7] += cb[j]*p1.w;
            }
#pragma unroll
            for (int k = 0; k < 8; ++k) {
                float x   = un[k] - bmax[m];
                float rvp = fmaxf(x, 0.f);        // relu(Ax - bmax)
                float spn = rvp - x;              // relu(bmax - Ax)  (new s+)
                float y   = un[k] - bmin[m];
                float smn = fmaxf(y, 0.f);        // relu(Ax - bmin)  (new s-)
                float rvm = smn - y;              // relu(bmin - Ax)
                res2 += rvp * rvp;
                res2 += rvm * rvm;
                h[k] = rvp - rvm;
                float xo  = uo[m][k] - bmax[m];
                float spo = fmaxf(-xo, 0.f);      // old s+
                float yo  = uo[m][k] - bmin[m];
                float smo = fmaxf(yo, 0.f);       // old s-
                float e1 = spn - spo;
                float e2 = smn - smo;
                ds2 += e1 * e1;
                ds2 += e2 * e2;
                uo[m][k] = un[k];
            }
#pragma unroll
            for (int j = 0; j < 16; ++j) {
                float4 p0 = *(const float4*)&Pt[m][j][4*l];
                float4 p1 = *(const float4*)&Pt[m][j][64 + 4*l];
                pjp[j] += h[0]*p0.x + h[1]*p0.y + h[2]*p0.z + h[3]*p0.w
                        + h[4]*p1.x + h[5]*p1.y + h[6]*p1.z + h[7]*p1.w;
            }
        }

        // butterfly reduce: pjp[16] + res2 + ds2 + cdel2 across the 16 lanes
#pragma unroll
        for (int s = 1; s < 16; s <<= 1) {
#pragma unroll
            for (int j = 0; j < 16; ++j) pjp[j] += __shfl_xor(pjp[j], s, 16);
            res2  += __shfl_xor(res2,  s, 16);
            ds2   += __shfl_xor(ds2,   s, 16);
            cdel2 += __shfl_xor(cdel2, s, 16);
        }

        // lane l extracts its component (static cndmask chain, no scratch)
        float pjl = pjp[0];
#pragma unroll
        for (int k = 1; k < 16; ++k) pjl = (l == k) ? pjp[k] : pjl;

        // ||lamda_new - lamda_old||^2 = sum pj^2 (replicated: all lanes have full pjp)
        float ln2 = 0.f;
#pragma unroll
        for (int k = 0; k < 16; ++k) ln2 += pjp[k] * pjp[k];

        L_l -= pjl;
        pj_l = pjl;

        if (l == 0) {
            res_st[t][g] = sqrtf(res2);
            fix_st[t][g] = sqrtf(ln2) + sqrtf(ds2) + sqrtf(cdel2);
        }
    }

    // ---- outputs ----
    out[ch * (BATCH * NVARS) + row * 16 + l] = c_l;   // lane l owns c[l]

    __syncthreads();
    const int t2 = threadIdx.x;
    if (t2 < 60) {
        int it = t2 % 15, r2 = t2 / 15, gb = r2 * 3;
        out[OUT_PST + it * BATCH + blockIdx.x * 4 + r2] =
            res_st[it][gb] + res_st[it][gb + 1] + res_st[it][gb + 2];
    } else if (t2 < 120) {
        int t3 = t2 - 60;
        int it = t3 % 15, r2 = t3 / 15, gb = r2 * 3;
        out[OUT_FST + it * BATCH + blockIdx.x * 4 + r2] =
            fix_st[it][gb] + fix_st[it][gb + 1] + fix_st[it][gb + 2];
    } else if (t2 < 124) {
        int r2 = t2 - 120, gb = r2 * 3;
        float s = 0.f;
        for (int it = 0; it < ITERS; ++it)
            s += fix_st[it][gb] + fix_st[it][gb + 1] + fix_st[it][gb + 2];
        out[OUT_ACCF + blockIdx.x * 4 + r2] = s * (1.f / 15.f);
    } else if (t2 < 128) {
        int r2 = t2 - 124, gb = r2 * 3;
        float s = 0.f;
        for (int it = 0; it < ITERS; ++it)
            s += res_st[it][gb] + res_st[it][gb + 1] + res_st[it][gb + 2];
        out[OUT_ACCP + blockIdx.x * 4 + r2] = s * (1.f / 15.f);
    }
}

extern "C" void kernel_launch(void* const* d_in, const int* in_sizes, int n_in,
                              void* d_out, int out_size, void* d_ws, size_t ws_size,
                              hipStream_t stream)
{
    const float* P    = (const float*)d_in[0];
    const float* Pdm  = (const float*)d_in[1];
    const float* Pddm = (const float*)d_in[2];
    const float* lamv = (const float*)d_in[3];
    const float* lamp = (const float*)d_in[4];
    const float* lamr = (const float*)d_in[5];
    const float* cinv = (const float*)d_in[6];
    const float* cinp = (const float*)d_in[7];
    const float* cinr = (const float*)d_in[8];
    const float* beqv = (const float*)d_in[9];
    const float* beqp = (const float*)d_in[10];
    const float* beqr = (const float*)d_in[11];
    const float* c0v  = (const float*)d_in[12];
    const float* c0p  = (const float*)d_in[13];
    const float* c0r  = (const float*)d_in[14];
    float* ws = (float*)d_ws;

    prep_kernel<<<1, 648, 0, stream>>>(P, Pdm, Pddm, ws);
    solve_kernel<<<2048, 192, 0, stream>>>(P, Pdm, Pddm,
        lamv, lamp, lamr, cinv, cinp, cinr,
        beqv, beqp, beqr, c0v, c0p, c0r,
        (float*)d_out, ws);
}

// Round 5
// 3074.868 us; speedup vs baseline: 1.9992x; 1.9992x over previous
//
#include <hip/hip_runtime.h>

#define NUMS   128
#define NVARS  16
#define BATCH  8192
#define ITERS  15

// d_out element offsets (return order: cv, cp, cr, acc_fixed, acc_primal, primal_stack, fixed_stack)
#define OUT_ACCF (3*BATCH*NVARS)           // 393216
#define OUT_ACCP (OUT_ACCF + BATCH)        // 401408
#define OUT_PST  (OUT_ACCP + BATCH)        // 409600
#define OUT_FST  (OUT_PST + ITERS*BATCH)   // 532480

// ---------------------------------------------------------------------------
// prep: AtA = 2(P^T P + Pd^T Pd + Pdd^T Pdd); cost_mat = [[I+AtA, Aeq^T],[Aeq,0]];
// M = inv(cost_mat) via f64 Gauss-Jordan. ws: [0,324) M row-major f32,
// [324,596) AtA padded [16][17] f32.
// ---------------------------------------------------------------------------
__global__ void prep_kernel(const float* __restrict__ P, const float* __restrict__ Pd,
                            const float* __restrict__ Pdd, float* __restrict__ ws)
{
    __shared__ double GA[18][36];
    __shared__ float  ata[16][16];
    __shared__ double piv_s;
    const int t = threadIdx.x;

    if (t < 256) {
        int j = t >> 4, k = t & 15;
        float s = 0.f;
        for (int i = 0; i < NUMS; ++i)
            s += P[i*16+j]*P[i*16+k] + Pd[i*16+j]*Pd[i*16+k] + Pdd[i*16+j]*Pdd[i*16+k];
        ata[j][k] = 2.f * s;
    }
    __syncthreads();

    const int gi = t / 36, gj = t % 36;   // blockDim = 648
    {
        double v;
        if (gj < 18) {
            if (gi < 16 && gj < 16)      v = (gi == gj ? 1.0 : 0.0) + (double)ata[gi][gj];
            else if (gi < 16)            v = (gj == 16) ? (double)P[gi] : (double)Pd[gi];
            else if (gj < 16)            v = (gi == 16) ? (double)P[gj] : (double)Pd[gj];
            else                         v = 0.0;
        } else {
            v = ((gj - 18) == gi) ? 1.0 : 0.0;
        }
        GA[gi][gj] = v;
    }
    __syncthreads();

    for (int k = 0; k < 18; ++k) {
        if (t == 0) piv_s = GA[k][k];
        __syncthreads();
        if (gi == k) GA[gi][gj] /= piv_s;
        __syncthreads();
        double f  = GA[gi][k];
        double rk = GA[k][gj];
        __syncthreads();
        if (gi != k) GA[gi][gj] -= f * rk;
        __syncthreads();
    }

    if (gj >= 18) ws[gi*18 + (gj - 18)] = (float)GA[gi][gj];
    if (t < 256)  ws[324 + (t >> 4)*17 + (t & 15)] = ata[t >> 4][t & 15];
    if (t >= 256 && t < 272) ws[324 + (t - 256)*17 + 16] = 0.f;
}

// ---------------------------------------------------------------------------
// main solver: block = 192 threads = 12 groups of 16 lanes = 4 rows x 3 channels.
// State is DISTRIBUTED: lane l of a group owns component l of c, L, cq, pj.
// __launch_bounds__(192,2): cap 256 VGPRs. R4's (192,4) forced a 64-VGPR cap
// -> ~100-float live set spilled -> 17.6 GB scratch traffic. Live set fits in
// ~128; actual occupancy then lands at 4 waves/EU from the real allocation.
// ---------------------------------------------------------------------------
__launch_bounds__(192, 2)
__global__ void solve_kernel(
    const float* __restrict__ P,    const float* __restrict__ Pd,   const float* __restrict__ Pdd,
    const float* __restrict__ lamv, const float* __restrict__ lamp, const float* __restrict__ lamr,
    const float* __restrict__ cinv, const float* __restrict__ cinp, const float* __restrict__ cinr,
    const float* __restrict__ beqv, const float* __restrict__ beqp, const float* __restrict__ beqr,
    const float* __restrict__ c0v,  const float* __restrict__ c0p,  const float* __restrict__ c0r,
    float* __restrict__ out, const float* __restrict__ ws)
{
    __shared__ __align__(16) float Pt[3][16][128];   // transposed: Pt[m][j][i]
    __shared__ float Ml[16][19];                     // M rows 0..15, cols 0..17 (pad 19)
    __shared__ float ata[16][17];
    __shared__ float res_st[ITERS][12];
    __shared__ float fix_st[ITERS][12];

    // ---- stage constants ----
#pragma unroll
    for (int m = 0; m < 3; ++m) {
        const float* src = (m == 0) ? P : (m == 1) ? Pd : Pdd;
        for (int f = threadIdx.x; f < 2048; f += 192) {
            int j = f >> 7, i = f & 127;
            Pt[m][j][i] = src[i*16 + j];
        }
    }
    for (int f = threadIdx.x; f < 288; f += 192) Ml[f / 18][f % 18] = ws[f];
    for (int f = threadIdx.x; f < 272; f += 192) ((float*)ata)[f] = ws[324 + f];
    __syncthreads();

    const int g  = threadIdx.x >> 4;   // group 0..11
    const int l  = threadIdx.x & 15;   // lane-in-group
    const int rl = g / 3;              // local row 0..3
    const int ch = g - rl * 3;         // channel 0..2
    const int row = blockIdx.x * 4 + rl;

    const float* lam_p = (ch == 0) ? lamv : (ch == 1) ? lamp : lamr;
    const float* cin_p = (ch == 0) ? cinv : (ch == 1) ? cinp : cinr;
    const float* beq_p = (ch == 0) ? beqv : (ch == 1) ? beqp : beqr;
    const float* c0_p  = (ch == 0) ? c0v  : (ch == 1) ? c0p  : c0r;

    // bounds per (ch, m)
    float bmax[3], bmin[3];
    bmax[0] = (ch == 0) ? 20.f : (ch == 1) ? 0.2f  : 0.25f;
    bmin[0] = (ch == 0) ? 12.f : (ch == 1) ? -0.2f : -0.25f;
    bmax[1] = (ch == 0) ? 3.f  : 0.25f;
    bmin[1] = (ch == 0) ? -3.f : -0.25f;
    bmax[2] = (ch == 0) ? 3.f  : 0.15f;
    bmin[2] = (ch == 0) ? -3.f : -0.15f;

    // ---- distributed per-unit state: lane l owns component l ----
    float c_l  = c0_p[row * 16 + l];
    float L_l  = lam_p[row * 16 + l] + cin_p[row * 16 + l];
    float pj_l, cq_l;
    const float beq0 = beq_p[row * 2];
    const float beq1 = beq_p[row * 2 + 1];
    float uo[3][8];                    // lane's 8 constraint rows per derivative order

    // ---- init pass: uo, pj0, cq0 from c0 ----
    {
        float cb[16];
#pragma unroll
        for (int k = 0; k < 16; ++k) cb[k] = __shfl(c_l, k, 16);

        float cqd = 0.f;
#pragma unroll
        for (int k = 0; k < 16; ++k) cqd += ata[l][k] * cb[k];
        cq_l = cqd;

        float pjp[16];
#pragma unroll
        for (int j = 0; j < 16; ++j) pjp[j] = 0.f;
#pragma unroll
        for (int m = 0; m < 3; ++m) {
            float un[8], h[8];
#pragma unroll
            for (int k = 0; k < 8; ++k) un[k] = 0.f;
#pragma unroll
            for (int j = 0; j < 16; ++j) {
                float4 p0 = *(const float4*)&Pt[m][j][4*l];
                float4 p1 = *(const float4*)&Pt[m][j][64 + 4*l];
                un[0] += cb[j]*p0.x; un[1] += cb[j]*p0.y; un[2] += cb[j]*p0.z; un[3] += cb[j]*p0.w;
                un[4] += cb[j]*p1.x; un[5] += cb[j]*p1.y; un[6] += cb[j]*p1.z; un[7] += cb[j]*p1.w;
            }
#pragma unroll
            for (int k = 0; k < 8; ++k) {
                float x = un[k] - bmax[m];
                float rvp = fmaxf(x, 0.f);
                float y = un[k] - bmin[m];
                float rvm = fmaxf(-y, 0.f);
                h[k] = rvp - rvm;
                uo[m][k] = un[k];
            }
#pragma unroll
            for (int j = 0; j < 16; ++j) {
                float4 p0 = *(const float4*)&Pt[m][j][4*l];
                float4 p1 = *(const float4*)&Pt[m][j][64 + 4*l];
                pjp[j] += h[0]*p0.x + h[1]*p0.y + h[2]*p0.z + h[3]*p0.w
                        + h[4]*p1.x + h[5]*p1.y + h[6]*p1.z + h[7]*p1.w;
            }
        }
#pragma unroll
        for (int s = 1; s < 16; s <<= 1) {
#pragma unroll
            for (int j = 0; j < 16; ++j) pjp[j] += __shfl_xor(pjp[j], s, 16);
        }
        float pjl = pjp[0];
#pragma unroll
        for (int k = 1; k < 16; ++k) pjl = (l == k) ? pjp[k] : pjl;
        pj_l = pjl;
    }

    // ---- 15 ADMM iterations ----
    for (int t = 0; t < ITERS; ++t) {
        // KKT solve: rhs_k = L_k + cq_k - pj_k (distributed); lane l owns M row l
        float r_l = L_l + cq_l - pj_l;
        float sj = Ml[l][16] * beq0 + Ml[l][17] * beq1;
#pragma unroll
        for (int k = 0; k < 16; ++k) sj += Ml[l][k] * __shfl(r_l, k, 16);

        float d = sj - c_l;
        float cdel2 = d * d;           // per-lane partial of ||c_new - c_old||^2
        c_l = sj;

        // broadcast new c
        float cb[16];
#pragma unroll
        for (int k = 0; k < 16; ++k) cb[k] = __shfl(c_l, k, 16);

        // cq for next solve: lane l computes (AtA c)_l
        float cqd = 0.f;
#pragma unroll
        for (int k = 0; k < 16; ++k) cqd += ata[l][k] * cb[k];
        cq_l = cqd;

        // projection passes
        float res2 = 0.f, ds2 = 0.f;
        float pjp[16];
#pragma unroll
        for (int j = 0; j < 16; ++j) pjp[j] = 0.f;

#pragma unroll
        for (int m = 0; m < 3; ++m) {
            float un[8], h[8];
#pragma unroll
            for (int k = 0; k < 8; ++k) un[k] = 0.f;
#pragma unroll
            for (int j = 0; j < 16; ++j) {
                float4 p0 = *(const float4*)&Pt[m][j][4*l];
                float4 p1 = *(const float4*)&Pt[m][j][64 + 4*l];
                un[0] += cb[j]*p0.x; un[1] += cb[j]*p0.y; un[2] += cb[j]*p0.z; un[3] += cb[j]*p0.w;
                un[4] += cb[j]*p1.x; un[5] += cb[j]*p1.y; un[6] += cb[j]*p1.z; un[7] += cb[j]*p1.w;
            }
#pragma unroll
            for (int k = 0; k < 8; ++k) {
                float x   = un[k] - bmax[m];
                float rvp = fmaxf(x, 0.f);        // relu(Ax - bmax)
                float spn = rvp - x;              // relu(bmax - Ax)  (new s+)
                float y   = un[k] - bmin[m];
                float smn = fmaxf(y, 0.f);        // relu(Ax - bmin)  (new s-)
                float rvm = smn - y;              // relu(bmin - Ax)
                res2 += rvp * rvp;
                res2 += rvm * rvm;
                h[k] = rvp - rvm;
                float xo  = uo[m][k] - bmax[m];
                float spo = fmaxf(-xo, 0.f);      // old s+
                float yo  = uo[m][k] - bmin[m];
                float smo = fmaxf(yo, 0.f);       // old s-
                float e1 = spn - spo;
                float e2 = smn - smo;
                ds2 += e1 * e1;
                ds2 += e2 * e2;
                uo[m][k] = un[k];
            }
#pragma unroll
            for (int j = 0; j < 16; ++j) {
                float4 p0 = *(const float4*)&Pt[m][j][4*l];
                float4 p1 = *(const float4*)&Pt[m][j][64 + 4*l];
                pjp[j] += h[0]*p0.x + h[1]*p0.y + h[2]*p0.z + h[3]*p0.w
                        + h[4]*p1.x + h[5]*p1.y + h[6]*p1.z + h[7]*p1.w;
            }
        }

        // butterfly reduce: pjp[16] + res2 + ds2 + cdel2 across the 16 lanes
#pragma unroll
        for (int s = 1; s < 16; s <<= 1) {
#pragma unroll
            for (int j = 0; j < 16; ++j) pjp[j] += __shfl_xor(pjp[j], s, 16);
            res2  += __shfl_xor(res2,  s, 16);
            ds2   += __shfl_xor(ds2,   s, 16);
            cdel2 += __shfl_xor(cdel2, s, 16);
        }

        // lane l extracts its component (static cndmask chain, no scratch)
        float pjl = pjp[0];
#pragma unroll
        for (int k = 1; k < 16; ++k) pjl = (l == k) ? pjp[k] : pjl;

        // ||lamda_new - lamda_old||^2 = sum pj^2 (replicated: all lanes have full pjp)
        float ln2 = 0.f;
#pragma unroll
        for (int k = 0; k < 16; ++k) ln2 += pjp[k] * pjp[k];

        L_l -= pjl;
        pj_l = pjl;

        if (l == 0) {
            res_st[t][g] = sqrtf(res2);
            fix_st[t][g] = sqrtf(ln2) + sqrtf(ds2) + sqrtf(cdel2);
        }
    }

    // ---- outputs ----
    out[ch * (BATCH * NVARS) + row * 16 + l] = c_l;   // lane l owns c[l]

    __syncthreads();
    const int t2 = threadIdx.x;
    if (t2 < 60) {
        int it = t2 % 15, r2 = t2 / 15, gb = r2 * 3;
        out[OUT_PST + it * BATCH + blockIdx.x * 4 + r2] =
            res_st[it][gb] + res_st[it][gb + 1] + res_st[it][gb + 2];
    } else if (t2 < 120) {
        int t3 = t2 - 60;
        int it = t3 % 15, r2 = t3 / 15, gb = r2 * 3;
        out[OUT_FST + it * BATCH + blockIdx.x * 4 + r2] =
            fix_st[it][gb] + fix_st[it][gb + 1] + fix_st[it][gb + 2];
    } else if (t2 < 124) {
        int r2 = t2 - 120, gb = r2 * 3;
        float s = 0.f;
        for (int it = 0; it < ITERS; ++it)
            s += fix_st[it][gb] + fix_st[it][gb + 1] + fix_st[it][gb + 2];
        out[OUT_ACCF + blockIdx.x * 4 + r2] = s * (1.f / 15.f);
    } else if (t2 < 128) {
        int r2 = t2 - 124, gb = r2 * 3;
        float s = 0.f;
        for (int it = 0; it < ITERS; ++it)
            s += res_st[it][gb] + res_st[it][gb + 1] + res_st[it][gb + 2];
        out[OUT_ACCP + blockIdx.x * 4 + r2] = s * (1.f / 15.f);
    }
}

extern "C" void kernel_launch(void* const* d_in, const int* in_sizes, int n_in,
                              void* d_out, int out_size, void* d_ws, size_t ws_size,
                              hipStream_t stream)
{
    const float* P    = (const float*)d_in[0];
    const float* Pdm  = (const float*)d_in[1];
    const float* Pddm = (const float*)d_in[2];
    const float* lamv = (const float*)d_in[3];
    const float* lamp = (const float*)d_in[4];
    const float* lamr = (const float*)d_in[5];
    const float* cinv = (const float*)d_in[6];
    const float* cinp = (const float*)d_in[7];
    const float* cinr = (const float*)d_in[8];
    const float* beqv = (const float*)d_in[9];
    const float* beqp = (const float*)d_in[10];
    const float* beqr = (const float*)d_in[11];
    const float* c0v  = (const float*)d_in[12];
    const float* c0p  = (const float*)d_in[13];
    const float* c0r  = (const float*)d_in[14];
    float* ws = (float*)d_ws;

    prep_kernel<<<1, 648, 0, stream>>>(P, Pdm, Pddm, ws);
    solve_kernel<<<2048, 192, 0, stream>>>(P, Pdm, Pddm,
        lamv, lamp, lamr, cinv, cinp, cinr,
        beqv, beqp, beqr, c0v, c0p, c0r,
        (float*)d_out, ws);
}